// Round 4
// baseline (311.427 us; speedup 1.0000x reference)
//
#include <hip/hip_runtime.h>

// ApsUp: polyphase 2x upsample (per-batch phase) + circular pad + depthwise
// 3x3 binomial blur, fused into a single gather kernel.
//
// Closed form per output (oy,ox), phase p (r=p&1, c=p>>1):
//   u=(oy-r)&127 -> rows i0=u>>1, i1=((u+1)&127)>>1 (dup when u even = weight 2)
//   v=(ox-c)&127 -> cols analogously; out = sum of 4 taps * 1/16.
//
// v5 = v4 with the launch bug fixed (grid was /4 too small: out_size is in
//      FLOATS, a plane is 128*128 floats -> 4096 blocks, not 1024).
//
// v4 design (deep per-thread loops; wave-churn was the residual, not stores):
//   - 1 block = 1 (b,ch) plane. 256 threads = 32 float2-cols x 8 row-groups.
//   - Each thread walks 9 input rows (rolling): row k+1's load AND its
//     shuffled edge value are reused as row k next iteration -> per thread
//     9 float2 loads + 9 shfls + 16 float4 stores (16 output rows).
//   - Stores full-line: each 32-lane group writes a contiguous 512B row seg.
//   - c (horizontal phase) is block-uniform: two template instantiations.

typedef float v4f __attribute__((ext_vector_type(4)));
typedef float v2f __attribute__((ext_vector_type(2)));

template<int C>
__device__ __forceinline__ void run_strip(const v2f* __restrict__ basef2,
                                          v4f* __restrict__ outp,
                                          const int j4, const int k0,
                                          const int r, const int src)
{
    // cur = input row k (cols 2j4, 2j4+1); curS = neighbor-lane edge element:
    //   C==0: next lane's .x (input col 2j4+2, wraps col 63 -> 0)
    //   C==1: prev lane's .y (input col 2j4-1, wraps col 0 -> 63)
    v2f  cur  = basef2[k0 * 32 + j4];
    float curS = __shfl(C == 0 ? cur.x : cur.y, src, 64);

    #pragma unroll
    for (int kk = 0; kk < 8; ++kk) {
        const int k = k0 + kk;
        const v2f  nxt  = basef2[((k + 1) & 63) * 32 + j4];   // wraps 63 -> 0
        const float nxtS = __shfl(C == 0 ? nxt.x : nxt.y, src, 64);

        // vertical blur column sums: u=2k (row k dup, weight 2), u=2k+1
        const v2f  sA = cur + cur;
        const v2f  sB = cur + nxt;
        const float eA = curS + curS;
        const float eB = curS + nxtS;

        v4f oA, oB;
        if (C == 0) {
            oA = (v4f){sA.x + sA.x, sA.x + sA.y, sA.y + sA.y, sA.y + eA};
            oB = (v4f){sB.x + sB.x, sB.x + sB.y, sB.y + sB.y, sB.y + eB};
        } else {
            oA = (v4f){eA + sA.x, sA.x + sA.x, sA.x + sA.y, sA.y + sA.y};
            oB = (v4f){eB + sB.x, sB.x + sB.x, sB.x + sB.y, sB.y + sB.y};
        }
        oA *= 0.0625f;
        oB *= 0.0625f;

        outp[((2 * k + r) & 127) * 32 + j4]     = oA;
        outp[((2 * k + 1 + r) & 127) * 32 + j4] = oB;

        cur = nxt; curS = nxtS;   // rolling reuse: no duplicate load or shfl
    }
}

__global__ __launch_bounds__(256) void aps_up_kernel(
    const float* __restrict__ inp,     // [16,256,64,64]
    const int*   __restrict__ phase,   // [16]
    float*       __restrict__ out)     // [16,256,128,128]
{
    // 1 block = 1 plane (b*256+ch); grid = 4096
    const int j4 = threadIdx.x & 31;        // float2-col (32 per 64-col input row)
    const int k0 = (threadIdx.x >> 5) * 8;  // first input row of this strip

    const int p = phase[blockIdx.x >> 8];   // uniform scalar load
    const int r = p & 1;
    const int c = p >> 1;

    const v2f* basef2 = reinterpret_cast<const v2f*>(inp) + (size_t)blockIdx.x * 2048;
    v4f*       outp   = reinterpret_cast<v4f*>(out)       + (size_t)blockIdx.x * 4096;

    const int grp = threadIdx.x & 32;       // 32-lane row-group base within wave
    if (c == 0) {
        run_strip<0>(basef2, outp, j4, k0, r, grp | ((j4 + 1) & 31));
    } else {
        run_strip<1>(basef2, outp, j4, k0, r, grp | ((j4 - 1) & 31));
    }
}

extern "C" void kernel_launch(void* const* d_in, const int* in_sizes, int n_in,
                              void* d_out, int out_size, void* d_ws, size_t ws_size,
                              hipStream_t stream) {
    const float* inp   = (const float*)d_in[0];
    const int*   phase = (const int*)d_in[1];
    float*       out   = (float*)d_out;

    // out_size = 16*256*128*128 floats; one block per 128*128-float plane
    const int grid = out_size / (128 * 128);           // 4096
    aps_up_kernel<<<grid, 256, 0, stream>>>(inp, phase, out);
}